// Round 2
// baseline (236.514 us; speedup 1.0000x reference)
//
#include <hip/hip_runtime.h>
#include <math.h>

// LeakyAvg: y[t] = k[t] + alpha_h * y[t-1], alpha_h = exp(-|beta_h|*10) in [e^-5, e^-0.5].
// alpha^16 <= e^-8 ~ 3.3e-4 -> 16-step zero-init halo warm-up, fully parallel chunks.
//
// R2 post-mortem: batching loads into kb[16] at SOURCE level did nothing --
// VGPR_Count stayed 32, proving the machine scheduler sank each load back down
// to sit just above its single use (legal: loads are independent, the FMA chain
// is serial, and sinking minimizes register pressure). Kernel remained
// ~4-deep-MLP latency-bound: 81us, 3.0 TB/s, VALUBusy 1.5%.
//
// R3 fix: __builtin_amdgcn_sched_barrier(0) between the load batch and the FMA
// chain. Mask 0 = NOTHING may cross -> all 16 loads must issue before the first
// consumer, forcing the allocator to keep 64 data VGPRs live (16-deep MLP,
// 16 KB/wave in flight; Little's law needs only ~9.5 KB/CU for full HBM BW).
// In-order consumption then gives descending partial vmcnt waits for free.
// Confirmation signal: VGPR_Count must jump to ~85-100.

typedef float f32x4 __attribute__((ext_vector_type(4)));

#define T_LEN 4096
#define H_DIM 16
#define D4 16                  // D=64 floats -> 16 float4 groups
#define CHUNK 16               // output rows per thread
#define WARM 16                // halo warm-up steps: alpha^16 = e^-8 error floor
#define CPB (T_LEN / CHUNK)    // 256 chunks per (b,h)

__device__ __forceinline__ f32x4 fma4(float a, f32x4 y, f32x4 kv) {
  f32x4 r;
  r.x = fmaf(a, y.x, kv.x);
  r.y = fmaf(a, y.y, kv.y);
  r.z = fmaf(a, y.z, kv.z);
  r.w = fmaf(a, y.w, kv.w);
  return r;
}

__global__ __launch_bounds__(256, 4) void leaky_avg_kernel(
    const f32x4* __restrict__ k,
    const float* __restrict__ beta,
    f32x4* __restrict__ out) {
  int idx = blockIdx.x * 256 + threadIdx.x;
  int d4 = idx & (D4 - 1);
  int g  = idx >> 4;             // g = bh * CPB + c (16 consecutive chunks per block)
  int c  = g & (CPB - 1);
  int bh = g >> 8;               // CPB = 256
  int h  = bh & (H_DIM - 1);

  float a = expf(-fabsf(beta[h]) * 10.0f);

  const f32x4* kp = k   + (size_t)bh * (T_LEN * D4) + d4;
  f32x4*       op = out + (size_t)bh * (T_LEN * D4) + d4;
  int t0 = c * CHUNK;

  f32x4 y = {0.f, 0.f, 0.f, 0.f};
  f32x4 kb[WARM];                // 64 VGPRs, reused by halo phase and main phase

  if (t0 >= WARM) {
    // phase A: halo warm-up [t0-WARM, t0).
    const f32x4* hp = kp + (size_t)(t0 - WARM) * D4;
    #pragma unroll
    for (int s = 0; s < WARM; ++s) kb[s] = hp[s * D4];
    // Pin: all 16 halo loads issue before the first FMA (nothing crosses).
    __builtin_amdgcn_sched_barrier(0);
    #pragma unroll
    for (int s = 0; s < WARM; ++s) y = fma4(a, y, kb[s]);
  }
  // (t0 == 0 needs no warm-up: reference scan starts from zero -> exact)

  // phase B: 16 main loads batched and pinned before the FMA+store chain.
  const f32x4* mp = kp + (size_t)t0 * D4;
  f32x4*       sp = op + (size_t)t0 * D4;
  #pragma unroll
  for (int s = 0; s < CHUNK; ++s) kb[s] = mp[s * D4];
  __builtin_amdgcn_sched_barrier(0);
  #pragma unroll
  for (int s = 0; s < CHUNK; ++s) {
    y = fma4(a, y, kb[s]);
    __builtin_nontemporal_store(y, &sp[s * D4]);
  }
}

extern "C" void kernel_launch(void* const* d_in, const int* in_sizes, int n_in,
                              void* d_out, int out_size, void* d_ws, size_t ws_size,
                              hipStream_t stream) {
  const f32x4* k    = (const f32x4*)d_in[0];   // (8,16,4096,64) fp32
  const float* beta = (const float*)d_in[1];   // (1,16,1,1) fp32
  f32x4*       out  = (f32x4*)d_out;           // (8,16,4096,64) fp32

  // total threads = B*H * CPB * D4 = 128 * 256 * 16 = 524288 -> 2048 blocks x 256
  const int total = 128 * CPB * D4;
  leaky_avg_kernel<<<dim3(total / 256), dim3(256), 0, stream>>>(k, beta, out);
}

// Round 3
// 234.815 us; speedup vs baseline: 1.0072x; 1.0072x over previous
//
#include <hip/hip_runtime.h>
#include <math.h>

// LeakyAvg: y[t] = k[t] + alpha_h * y[t-1], alpha_h = exp(-|beta_h|*10) in [e^-5, e^-0.5].
// alpha^16 <= e^-8 ~ 3.3e-4 -> 16-step zero-init halo warm-up, fully parallel chunks.
//
// R3 post-mortem: sched_barrier(0) moved VGPR only 32->40 -- scheduler still
// collapsed the batch to ~2-3 loads in flight; 83us / 2.8 TB/s unchanged.
// Little's law on the measured BW: 2.8 TB/s x 375ns = 4.1 KB/CU outstanding
// = ~0.3 loads/wave average -- waves sit in vmcnt(0) stalls with an EMPTY pipe.
//
// R4: inline-asm global_load_dwordx4. "=v" outputs mechanically force 16
// results (64 data VGPRs) live; asm volatile order forces all 16 to issue
// back-to-back before one explicit s_waitcnt vmcnt(0). sched_barrier(0) after
// each waitcnt per guide rule #18 (hipcc hoists reg-only ops past asm waitcnt).
// All 16 loads share one base VGPR pair + imm offset:0..3840.
// Confirmation: VGPR_Count must land ~85-100 (allocator has no choice).

typedef float f32x4 __attribute__((ext_vector_type(4)));

#define T_LEN 4096
#define H_DIM 16
#define D4 16                  // D=64 floats -> 16 float4 groups
#define CHUNK 16               // output rows per thread
#define WARM 16                // halo warm-up steps: alpha^16 = e^-8 error floor
#define CPB (T_LEN / CHUNK)    // 256 chunks per (b,h)

__device__ __forceinline__ f32x4 fma4(float a, f32x4 y, f32x4 kv) {
  f32x4 r;
  r.x = fmaf(a, y.x, kv.x);
  r.y = fmaf(a, y.y, kv.y);
  r.z = fmaf(a, y.z, kv.z);
  r.w = fmaf(a, y.w, kv.w);
  return r;
}

// 16 back-to-back 16B loads from one base, immediate offsets 0..3840 (t-stride 256B).
#define GLOAD(i, dst, base, OFF)                                   \
  asm volatile("global_load_dwordx4 %0, %1, off offset:" #OFF     \
               : "=v"(dst) : "v"(base))

#define GLOAD16(kb, base)              \
  GLOAD(0,  kb[0],  base, 0);          \
  GLOAD(1,  kb[1],  base, 256);        \
  GLOAD(2,  kb[2],  base, 512);        \
  GLOAD(3,  kb[3],  base, 768);        \
  GLOAD(4,  kb[4],  base, 1024);       \
  GLOAD(5,  kb[5],  base, 1280);       \
  GLOAD(6,  kb[6],  base, 1536);       \
  GLOAD(7,  kb[7],  base, 1792);       \
  GLOAD(8,  kb[8],  base, 2048);       \
  GLOAD(9,  kb[9],  base, 2304);       \
  GLOAD(10, kb[10], base, 2560);       \
  GLOAD(11, kb[11], base, 2816);       \
  GLOAD(12, kb[12], base, 3072);       \
  GLOAD(13, kb[13], base, 3328);       \
  GLOAD(14, kb[14], base, 3584);       \
  GLOAD(15, kb[15], base, 3840)

#define VM_DRAIN()                                      \
  asm volatile("s_waitcnt vmcnt(0)" ::: "memory");      \
  __builtin_amdgcn_sched_barrier(0)

__global__ __launch_bounds__(256, 4) void leaky_avg_kernel(
    const f32x4* __restrict__ k,
    const float* __restrict__ beta,
    f32x4* __restrict__ out) {
  int idx = blockIdx.x * 256 + threadIdx.x;
  int d4 = idx & (D4 - 1);
  int g  = idx >> 4;             // g = bh * CPB + c (16 consecutive chunks per block)
  int c  = g & (CPB - 1);
  int bh = g >> 8;               // CPB = 256
  int h  = bh & (H_DIM - 1);

  float a = expf(-fabsf(beta[h]) * 10.0f);

  const f32x4* kp = k   + (size_t)bh * (T_LEN * D4) + d4;
  f32x4*       op = out + (size_t)bh * (T_LEN * D4) + d4;
  int t0 = c * CHUNK;

  f32x4 y = {0.f, 0.f, 0.f, 0.f};
  f32x4 kb[16];                  // 64 VGPRs, forced live by asm "=v" outputs

  if (t0 >= WARM) {
    // phase A: halo warm-up [t0-WARM, t0): 16 loads issue, one drain, 16 FMAs.
    const f32x4* hp = kp + (size_t)(t0 - WARM) * D4;
    GLOAD16(kb, hp);
    VM_DRAIN();
    #pragma unroll
    for (int s = 0; s < WARM; ++s) y = fma4(a, y, kb[s]);
  }
  // (t0 == 0 needs no warm-up: reference scan starts from zero -> exact)

  // phase B: 16 main loads, one drain, FMA+store (stores fire-and-forget).
  const f32x4* mp = kp + (size_t)t0 * D4;
  f32x4*       sp = op + (size_t)t0 * D4;
  GLOAD16(kb, mp);
  VM_DRAIN();
  #pragma unroll
  for (int s = 0; s < CHUNK; ++s) {
    y = fma4(a, y, kb[s]);
    __builtin_nontemporal_store(y, &sp[s * D4]);
  }
}

extern "C" void kernel_launch(void* const* d_in, const int* in_sizes, int n_in,
                              void* d_out, int out_size, void* d_ws, size_t ws_size,
                              hipStream_t stream) {
  const f32x4* k    = (const f32x4*)d_in[0];   // (8,16,4096,64) fp32
  const float* beta = (const float*)d_in[1];   // (1,16,1,1) fp32
  f32x4*       out  = (f32x4*)d_out;           // (8,16,4096,64) fp32

  // total threads = B*H * CPB * D4 = 128 * 256 * 16 = 524288 -> 2048 blocks x 256
  const int total = 128 * CPB * D4;
  leaky_avg_kernel<<<dim3(total / 256), dim3(256), 0, stream>>>(k, beta, out);
}

// Round 4
// 232.806 us; speedup vs baseline: 1.0159x; 1.0086x over previous
//
#include <hip/hip_runtime.h>
#include <math.h>

// LeakyAvg: y[t] = k[t] + alpha_h * y[t-1], alpha = exp(-|beta|*10) in [e^-5, e^-0.5].
// alpha^16 <= e^-8 -> 16-row zero-init halo warm-up per chunk, fully parallel.
//
// R4 post-mortem of R1-R3: BW pinned at 2.6-2.8 TB/s regardless of per-wave MLP
// depth (2-deep compiler shape == 16-deep forced-asm shape) => NOT latency-bound;
// it's a THROUGHPUT cap of the access pattern. d4=idx&15 mapping makes every
// wave-load 4x 256B segments 4KB apart -> scattered 256B requests on a 4KB grid
// chip-wide -> HBM row thrash (~40% efficiency ~ 2.6 TB/s). Contiguous streams on
// the same chip hit 6.3-6.8 TB/s (fill kernel, m13 float4 copy).
//
// R4: LDS-staged linear streaming.
//   1. global_load_lds DMA (fire-and-forget, vmcnt-counted, no dest VGPRs ->
//      scheduler can't sink it): block stages [t0-16, t0+128) rows = 36.9 KB as a
//      SEQUENTIAL stream, 1 KB contiguous per wave-issue, ~18 in flight per wave.
//   2. recurrence reads LDS (the 4KB-stride gather moves to LDS where it's cheap).
//   3. outputs overwrite consumed input rows in LDS (halo readers done pre-barrier),
//      then stream out as contiguous 1 KB/wave plain stores (no nt L2-bypass).
// Occupancy 8 waves/CU (LDS-limited) is intentional: DMA depth >> Little's law.

typedef float f32x4 __attribute__((ext_vector_type(4)));

#define T_LEN 4096
#define H_DIM 16
#define ROW_B 256                          // bytes per row (D=64 fp32)
#define D4 16                              // f32x4 per row
#define HALO 16
#define MAIN_ROWS 128                      // output rows per block
#define LDS_ROWS (MAIN_ROWS + HALO)        // 144
#define LDS_BYTES (LDS_ROWS * ROW_B)       // 36864 (< 64 KB static limit)
#define THREADS 128                        // 8 chunks x 16 d4 = 2 waves
#define NWAVES (THREADS / 64)              // 2
#define WCHUNKS (LDS_BYTES / 1024)         // 36 x 1KB wave-chunks
#define DMA_ITERS (WCHUNKS / NWAVES)       // 18 per wave
#define BLOCKS_PER_BH (T_LEN / MAIN_ROWS)  // 32
#define OUT_BYTES (MAIN_ROWS * ROW_B)      // 32768

__device__ __forceinline__ f32x4 fma4(float a, f32x4 y, f32x4 kv) {
  f32x4 r;
  r.x = fmaf(a, y.x, kv.x);
  r.y = fmaf(a, y.y, kv.y);
  r.z = fmaf(a, y.z, kv.z);
  r.w = fmaf(a, y.w, kv.w);
  return r;
}

__global__ __launch_bounds__(THREADS, 2) void leaky_avg_kernel(
    const float* __restrict__ k,
    const float* __restrict__ beta,
    float* __restrict__ out) {
  __shared__ __align__(16) unsigned char lds_raw[LDS_BYTES];

  const int tid = threadIdx.x;
  const int bid = blockIdx.x;
  const int bh  = bid >> 5;                       // BLOCKS_PER_BH = 32
  const int bc  = bid & (BLOCKS_PER_BH - 1);
  const int h   = bh & (H_DIM - 1);
  const float a = expf(-fabsf(beta[h]) * 10.0f);

  const size_t bh_byte = (size_t)bh * ((size_t)T_LEN * ROW_B);
  const int t0_blk = bc * MAIN_ROWS;              // first output row of this block

  // ---- phase 1: DMA rows [t0_blk-HALO, t0_blk+MAIN_ROWS) linearly into LDS ----
  {
    const int wave = tid >> 6;
    const int lane = tid & 63;
    const char* kc = (const char*)k + bh_byte;
    #pragma unroll
    for (int i = 0; i < DMA_ITERS; ++i) {
      const int q    = i * NWAVES + wave;         // 0..35, wave-uniform
      const int loff = q * 1024 + lane * 16;      // linear: lane stride 16B (HW requirement)
      int goff = (t0_blk - HALO) * ROW_B + loff;  // block-relative byte in k
      // bc==0: halo rows t=-16..-1 don't exist; shift those chunks onto rows 0..15.
      // The filled slots are never consumed (cl==0 skips its halo when bc==0).
      if (goff < 0) goff += HALO * ROW_B;
      __builtin_amdgcn_global_load_lds(
          (const __attribute__((address_space(1))) void*)(kc + goff),
          (__attribute__((address_space(3))) void*)(lds_raw + loff),
          16, 0, 0);
    }
  }
  asm volatile("s_waitcnt vmcnt(0)" ::: "memory");  // drain DMA (insurance; syncthreads also drains)
  __syncthreads();

  // ---- phase 2: per-thread recurrence out of LDS ----
  const int d4i   = tid & (D4 - 1);
  const int cl    = tid >> 4;                     // chunk-in-block 0..7
  const int rbase = cl * 16;                      // block-local row of halo start
  const f32x4* ldsv = (const f32x4*)lds_raw;

  f32x4 y = {0.f, 0.f, 0.f, 0.f};
  if (!(bc == 0 && cl == 0)) {                    // t0==0 chunk: scan starts at zero, exact
    f32x4 hreg[HALO];
    #pragma unroll
    for (int s = 0; s < HALO; ++s) hreg[s] = ldsv[(rbase + s) * D4 + d4i];
    #pragma unroll
    for (int s = 0; s < HALO; ++s) y = fma4(a, y, hreg[s]);
  }

  f32x4 yreg[16];
  {
    f32x4 mreg[16];
    #pragma unroll
    for (int s = 0; s < 16; ++s) mreg[s] = ldsv[(rbase + HALO + s) * D4 + d4i];
    #pragma unroll
    for (int s = 0; s < 16; ++s) { y = fma4(a, y, mreg[s]); yreg[s] = y; }
  }

  __syncthreads();   // all input reads (incl. neighbor halo) complete before overwrite

  // ---- phase 3a: outputs overwrite their input rows in LDS ----
  {
    f32x4* ldsw = (f32x4*)lds_raw;
    #pragma unroll
    for (int s = 0; s < 16; ++s) ldsw[(rbase + HALO + s) * D4 + d4i] = yreg[s];
  }
  __syncthreads();

  // ---- phase 3b: stream LDS[HALO..] out linearly (1 KB contiguous per wave-store) ----
  {
    const char* lsrc = (const char*)lds_raw + HALO * ROW_B;
    char* odst = (char*)out + bh_byte + (size_t)t0_blk * ROW_B;
    #pragma unroll
    for (int i = 0; i < OUT_BYTES / (THREADS * 16); ++i) {  // 16 slices of 2 KB
      const int o = i * (THREADS * 16) + tid * 16;
      *(f32x4*)(odst + o) = *(const f32x4*)(lsrc + o);
    }
  }
}

extern "C" void kernel_launch(void* const* d_in, const int* in_sizes, int n_in,
                              void* d_out, int out_size, void* d_ws, size_t ws_size,
                              hipStream_t stream) {
  const float* k    = (const float*)d_in[0];   // (8,16,4096,64) fp32
  const float* beta = (const float*)d_in[1];   // (1,16,1,1) fp32
  float*       out  = (float*)d_out;           // (8,16,4096,64) fp32

  // blocks = B*H * T/MAIN_ROWS = 128 * 32 = 4096, 128 threads each
  leaky_avg_kernel<<<dim3(128 * BLOCKS_PER_BH), dim3(THREADS), 0, stream>>>(k, beta, out);
}